// Round 11
// baseline (261.364 us; speedup 1.0000x reference)
//
#include <hip/hip_runtime.h>

// Problem constants
constexpr int Bb = 4;     // batch
constexpr int Dd = 256;   // channels
constexpr int Nn = 2048;  // query positions
constexpr int Mm = 2048;  // source positions
constexpr int Hh = 4;     // heads
constexpr int D2 = 512;   // 2*D
constexpr int NT = Bb * Nn;  // 8192 total positions

#define FMAXV 3.402823466e38f

typedef _Float16 half8 __attribute__((ext_vector_type(8)));
typedef _Float16 half4v __attribute__((ext_vector_type(4)));
typedef _Float16 half2v __attribute__((ext_vector_type(2)));
typedef float f32x4 __attribute__((ext_vector_type(4)));

typedef const __attribute__((address_space(1))) void* gas_p;
typedef __attribute__((address_space(3))) void* las_p;

__device__ __forceinline__ void gload16(const void* g, void* l) {
    __builtin_amdgcn_global_load_lds((gas_p)g, (las_p)l, 16, 0, 0);
}

// ---------------------------------------------------------------------------
// Fused prepack: weights + bitmask + activation transpose (unchanged)
// ---------------------------------------------------------------------------
__global__ __launch_bounds__(256)
void prep_all_kernel(const float* __restrict__ Wq, const float* __restrict__ bq,
                     const float* __restrict__ Wk, const float* __restrict__ bk,
                     const float* __restrict__ Wv, const float* __restrict__ bv,
                     const float* __restrict__ Wm,
                     const float* __restrict__ W1, const float* __restrict__ b1,
                     const float* __restrict__ gamma, const float* __restrict__ beta,
                     const float* __restrict__ rmean, const float* __restrict__ rvar,
                     const float* __restrict__ W2, const float* __restrict__ mask,
                     const float* __restrict__ x, const float* __restrict__ source,
                     _Float16* __restrict__ Wqp, float* __restrict__ bqp,
                     _Float16* __restrict__ Wkvp, float* __restrict__ bkvp,
                     _Float16* __restrict__ Wmp,
                     _Float16* __restrict__ W1p, float* __restrict__ b1f,
                     _Float16* __restrict__ W2p,
                     unsigned long long* __restrict__ bmask,
                     _Float16* __restrict__ Yp, _Float16* __restrict__ Sp) {
    const int r = blockIdx.x, t = threadIdx.x;
    if (r < 256) {
        const int h = r >> 6, d = r & 63, so = d * Hh + h;
        Wqp[r * 256 + t] = (_Float16)Wq[so * 256 + t];
        if (t == 0) bqp[r] = bq[so];
    } else if (r < 768) {
        const int rr = r - 256, part = rr >> 8, o = rr & 255;
        const int h = o >> 6, d = o & 63, so = d * Hh + h;
        const float* Ws = part ? Wv : Wk;
        const float* bs = part ? bv : bk;
        Wkvp[rr * 256 + t] = (_Float16)Ws[so * 256 + t];
        if (t == 0) bkvp[rr] = bs[so];
    } else if (r < 1024) {
        const int o = r - 768;
        const int h = t >> 6, d = t & 63, sk = d * Hh + h;
        Wmp[o * 256 + t] = (_Float16)Wm[o * 256 + sk];
    } else if (r < 1536) {
        const int o = r - 1024;
        const float s = gamma[o] * rsqrtf(rvar[o] + 1e-3f);
        W1p[o * 512 + t]       = (_Float16)(W1[o * 512 + t] * s);
        W1p[o * 512 + t + 256] = (_Float16)(W1[o * 512 + t + 256] * s);
        if (t == 0) b1f[o] = (b1[o] - rmean[o]) * s + beta[o];
    } else if (r < 1792) {
        const int o = r - 1536;
        W2p[o * 512 + t]       = (_Float16)W2[o * 512 + t];
        W2p[o * 512 + t + 256] = (_Float16)W2[o * 512 + t + 256];
    } else if (r < 3840) {
        const int id = r - 1792;               // 0..2047
        const int w = t >> 6, lane = t & 63;
        const int row = id * 4 + w;            // 0..8191
        const float* mrow = mask + (size_t)row * Mm;
        unsigned long long* brow = bmask + (size_t)row * (Mm / 64);
        #pragma unroll 4
        for (int word = 0; word < Mm / 64; ++word) {
            const float v = mrow[word * 64 + lane];
            const unsigned long long bits = __ballot(v > 0.f);
            if (lane == 0) brow[word] = bits;
        }
    } else {
        __shared__ _Float16 Ts[64][72];
        const int px = r - 3840;
        const int n0 = (px & 31) * 64, c0 = ((px >> 5) & 3) * 64;
        const int z = px >> 7, b = z >> 1, which = z & 1;
        const float* src = which ? source : x;
        _Float16* dst = which ? Sp : Yp;
        const int stride = which ? 256 : 512;
        const int cl = t >> 2, np = (t & 3) * 16;
        const float* sp = src + ((size_t)b * Dd + c0 + cl) * Nn + n0 + np;
        #pragma unroll
        for (int i = 0; i < 4; ++i) {
            float4 v = *(const float4*)(sp + i * 4);
            Ts[np + i * 4 + 0][cl] = (_Float16)v.x;
            Ts[np + i * 4 + 1][cl] = (_Float16)v.y;
            Ts[np + i * 4 + 2][cl] = (_Float16)v.z;
            Ts[np + i * 4 + 3][cl] = (_Float16)v.w;
        }
        __syncthreads();
        const int nl = t >> 2, cp = (t & 3) * 16;
        half8 a0 = *(const half8*)&Ts[nl][cp];
        half8 a1 = *(const half8*)&Ts[nl][cp + 8];
        _Float16* dp = dst + ((size_t)b * Nn + n0 + nl) * stride + c0 + cp;
        *(half8*)dp = a0;
        *(half8*)(dp + 8) = a1;
    }
}

// ---------------------------------------------------------------------------
// GEMM (R7 structure, unchanged): BM=128 BN=64, gload_lds staging + XOR
// swizzle, LDS 48 KB, coalesced transpose epilogues for V / fp32 out.
// ---------------------------------------------------------------------------
__global__ __launch_bounds__(256)
void gemm4w_kernel(const _Float16* __restrict__ A, const _Float16* __restrict__ A2,
                   const _Float16* __restrict__ W, const float* __restrict__ bias,
                   _Float16* __restrict__ dst0, _Float16* __restrict__ dst1,
                   _Float16* __restrict__ dst2, float* __restrict__ dstF,
                   int K, int sA, int sOut, int modeSel, int relu, float oscale) {
    __shared__ __align__(16) _Float16 As[2 * 128 * 64];   // 32 KB
    __shared__ __align__(16) _Float16 Bs[2 * 64 * 64];    // 16 KB

    const int t = threadIdx.x;
    const int w = t >> 6, lane = t & 63, quad = lane >> 4, l16 = lane & 15;
    const int n0 = blockIdx.x * 128;
    const int og0 = blockIdx.y * 64;

    int mode = 0, oloc0 = og0;
    const _Float16* Ab = A;
    int sAl = sA;
    _Float16* d0 = dst0;
    float osc = oscale;
    if (modeSel == 3) {
        const int part = blockIdx.y >> 2;               // 0=Q, 1=K, 2=V
        if (part == 1)      { Ab = A2; sAl = 256; d0 = dst1; oloc0 = og0 - 256; osc = 1.0f; }
        else if (part == 2) { Ab = A2; sAl = 256; mode = 1; oloc0 = og0 - 512; osc = 1.0f; }
    } else if (modeSel == 2) {
        mode = 2;
    }

    const int srow = t >> 3, sslot = t & 7;
    const int schunk = sslot ^ (srow & 7);

    f32x4 acc[2][4] = {};
    const int nk = K / 64;
    int buf = 0;

    {
        #pragma unroll
        for (int c = 0; c < 4; ++c)
            gload16(Ab + (size_t)(n0 + c * 32 + srow) * sAl + schunk * 8,
                    As + c * 2048 + t * 8);
        #pragma unroll
        for (int c = 0; c < 2; ++c)
            gload16(W + (size_t)(og0 + c * 32 + srow) * K + schunk * 8,
                    Bs + c * 2048 + t * 8);
        __asm__ volatile("s_waitcnt vmcnt(0)" ::: "memory");
        __syncthreads();
    }

    #pragma unroll 1
    for (int kt = 0; kt < nk; ++kt) {
        if (kt + 1 < nk) {
            const int k0 = (kt + 1) * 64, nb = buf ^ 1;
            #pragma unroll
            for (int c = 0; c < 4; ++c)
                gload16(Ab + (size_t)(n0 + c * 32 + srow) * sAl + k0 + schunk * 8,
                        As + nb * 8192 + c * 2048 + t * 8);
            #pragma unroll
            for (int c = 0; c < 2; ++c)
                gload16(W + (size_t)(og0 + c * 32 + srow) * K + k0 + schunk * 8,
                        Bs + nb * 4096 + c * 2048 + t * 8);
        }
        #pragma unroll
        for (int ks = 0; ks < 2; ++ks) {
            const int csw = ((ks * 4 + quad) ^ (l16 & 7)) * 8;
            half8 af[2], bf[4];
            #pragma unroll
            for (int i = 0; i < 2; ++i)
                af[i] = *(const half8*)&As[buf * 8192 + (w * 32 + i * 16 + l16) * 64 + csw];
            #pragma unroll
            for (int j = 0; j < 4; ++j)
                bf[j] = *(const half8*)&Bs[buf * 4096 + (j * 16 + l16) * 64 + csw];
            #pragma unroll
            for (int i = 0; i < 2; ++i)
                #pragma unroll
                for (int j = 0; j < 4; ++j)
                    acc[i][j] = __builtin_amdgcn_mfma_f32_16x16x32_f16(af[i], bf[j], acc[i][j], 0, 0, 0);
        }
        if (kt + 1 < nk) {
            __asm__ volatile("s_waitcnt vmcnt(0)" ::: "memory");
            __syncthreads();
            buf ^= 1;
        }
    }

    float bcol[4];
    #pragma unroll
    for (int j = 0; j < 4; ++j) bcol[j] = bias[og0 + j * 16 + l16];

    if (mode == 0) {
        _Float16* Escr = As + w * 2048;
        #pragma unroll
        for (int i = 0; i < 2; ++i) {
            #pragma unroll
            for (int j = 0; j < 4; ++j)
                #pragma unroll
                for (int reg = 0; reg < 4; ++reg) {
                    float v = (acc[i][j][reg] + bcol[j]) * osc;
                    if (relu) v = fmaxf(v, 0.f);
                    Escr[(quad * 4 + reg) * 72 + j * 16 + l16] = (_Float16)v;
                }
            __asm__ volatile("s_waitcnt lgkmcnt(0)" ::: "memory");
            const int row = lane & 15, oseg = (lane >> 4) * 16;
            half8 e0 = *(const half8*)&Escr[row * 72 + oseg];
            half8 e1 = *(const half8*)&Escr[row * 72 + oseg + 8];
            _Float16* dp = d0 + (size_t)(n0 + w * 32 + i * 16 + row) * sOut + oloc0 + oseg;
            *(half8*)dp = e0;
            *(half8*)(dp + 8) = e1;
            __asm__ volatile("s_waitcnt lgkmcnt(0)" ::: "memory");
        }
    } else if (mode == 1) {
        #pragma unroll
        for (int i = 0; i < 2; ++i)
            #pragma unroll
            for (int j = 0; j < 4; ++j) {
                const int c = j * 16 + l16;
                const int mloc = w * 32 + i * 16 + quad * 4;
                const int sw = l16 * 8;
                half4v pv;
                #pragma unroll
                for (int reg = 0; reg < 4; ++reg)
                    pv[reg] = (_Float16)(acc[i][j][reg] + bcol[j]);
                *(half4v*)&As[c * 128 + (mloc ^ sw)] = pv;
            }
        __syncthreads();
        const int n0m = n0 & 2047, bidx = n0 >> 11;
        #pragma unroll
        for (int r = 0; r < 2; ++r) {
            const int c = (t >> 3) + r * 32;
            const int mch = (t & 7) * 16;
            const int sw = (c & 15) * 8;
            half8 v0 = *(const half8*)&As[c * 128 + (mch ^ sw)];
            half8 v1 = *(const half8*)&As[c * 128 + ((mch + 8) ^ sw)];
            _Float16* dp = dst2 + ((size_t)bidx * 256 + oloc0 + c) * (size_t)Mm + n0m + mch;
            *(half8*)dp = v0;
            *(half8*)(dp + 8) = v1;
        }
    } else {
        __syncthreads();
        float* scr = (float*)As;
        #pragma unroll
        for (int i = 0; i < 2; ++i)
            #pragma unroll
            for (int j = 0; j < 4; ++j) {
                const int c = j * 16 + l16;
                const int mloc = w * 32 + i * 16 + quad * 4;
                const int sw = (c & 7) * 4;
                f32x4 v;
                #pragma unroll
                for (int reg = 0; reg < 4; ++reg) v[reg] = acc[i][j][reg] + bcol[j];
                *(f32x4*)&scr[c * 128 + (mloc ^ sw)] = v;
            }
        __syncthreads();
        const int n0m = n0 & 2047, bidx = n0 >> 11;
        #pragma unroll
        for (int r = 0; r < 2; ++r) {
            const int c = (t >> 3) + r * 32;
            const int mch = (t & 7) * 16;
            const int sw = (c & 7) * 4;
            float* dp = dstF + ((size_t)bidx * 256 + og0 + c) * (size_t)Nn + n0m + mch;
            #pragma unroll
            for (int k = 0; k < 4; ++k)
                *(f32x4*)(dp + k * 4) = *(const f32x4*)&scr[c * 128 + ((mch + k * 4) ^ sw)];
        }
    }
}

// ---------------------------------------------------------------------------
// MFMA attention R11: 8-wave blocks at FULL occupancy.
// R7-R10 evidence: attn pinned at ~44.5us across conflict/VALU/layout fixes
// with every pipe <55% and occupancy 29% (16 waves/CU) -> TLP-starved
// latency chain. This round doubles residency: 512-thr blocks (8 waves,
// 128 q-rows) x m-split x4, grid 1024 -> 4 blocks/CU x 8 waves = 32
// waves/CU (hardware max). Side effects: K/V global traffic halves
// (tile shared by 128 rows), iterations/block halve (8), barrier count
// per q-row halves. LDS 34.8 KB -> 4 blocks/CU. launch_bounds(512,8)
// pins VGPR<=64 (R10 used 60). Internals (swapped QK^T, exp2, bitmask)
// unchanged from R10.
// ---------------------------------------------------------------------------
__global__ __launch_bounds__(512, 8)
void attn_mfma_kernel(const _Float16* __restrict__ Qp, const _Float16* __restrict__ Kp,
                      const _Float16* __restrict__ Vt,
                      const unsigned int* __restrict__ bmask,
                      _Float16* __restrict__ Oa, _Float16* __restrict__ Ob,
                      _Float16* __restrict__ Oc, _Float16* __restrict__ Od,
                      float* __restrict__ La, float* __restrict__ Lb,
                      float* __restrict__ Lc, float* __restrict__ Ld) {
    __shared__ __align__(16) _Float16 Ks[64][64];      // 8192 B, swizzled
    __shared__ __align__(16) _Float16 Vs[64][64];      // 8192 B, swizzled
    __shared__ __align__(16) _Float16 Ps[8][16][72];   // 18432 B

    // XCD-aware decomposition: id%8 = XCD slot -> bh pair
    const int id = blockIdx.x;
    const int xcd = id & 7, loc = id >> 3;             // loc 0..127
    const int bh = xcd * 2 + (loc >> 6);               // 0..15
    const int sub = loc & 63;
    const int mquart = sub & 3;
    const int n0 = (sub >> 2) * 128;                   // 16 tiles of 128 rows
    const int b = bh >> 2, h = bh & 3;

    const int t = threadIdx.x;
    const int w = t >> 6, lane = t & 63, quad = lane >> 4, l16 = lane & 15;

    const _Float16* qp = Qp + ((size_t)b * Nn + n0 + w * 16 + l16) * 256 + h * 64 + quad * 8;
    const half8 qa0 = *(const half8*)(qp);
    const half8 qa1 = *(const half8*)(qp + 32);

    const _Float16* Kstg = Kp + (size_t)b * Nn * 256 + h * 64;
    const _Float16* Vstg = Vt + ((size_t)b * 256 + h * 64) * (size_t)Mm;
    // staging: 512 threads, each one 16B chunk of K and of V.
    const int sr = t >> 3;                             // row 0..63
    const int sl = t & 7;                              // 16B slot 0..7
    const int ss = sl ^ (sr & 7);                      // swizzled slot

    // per-lane bitmask row: q = n0 + w*16 + l16
    const unsigned int* bmRow = bmask + ((size_t)b * Nn + n0 + w * 16 + l16) * (Mm / 32);

    _Float16* Odst = mquart == 0 ? Oa : mquart == 1 ? Ob : mquart == 2 ? Oc : Od;
    float*    Ldst = mquart == 0 ? La : mquart == 1 ? Lb : mquart == 2 ? Lc : Ld;
    const int mbeg = mquart * (Mm / 4);

    float psum = 0.f;
    f32x4 O[4] = {};

    half8 sk, sv;
    auto stage_load = [&](int m0) {
        sk = *(const half8*)(Kstg + (size_t)(m0 + sr) * 256 + sl * 8);
        sv = *(const half8*)(Vstg + (size_t)sr * Mm + m0 + sl * 8);
    };
    auto stage_write = [&]() {
        *(half8*)&Ks[sr][ss * 8] = sk;
        *(half8*)&Vs[sr][ss * 8] = sv;
    };

    stage_load(mbeg);
    stage_write();
    __syncthreads();

    #pragma unroll 1
    for (int it = 0; it < (Mm / 4) / 64; ++it) {
        const int m0 = mbeg + it * 64;
        if (it < (Mm / 4) / 64 - 1) stage_load(m0 + 64);

        const uint2 bmv = *(const uint2*)(bmRow + (m0 >> 5));

        f32x4 S[4];
        #pragma unroll
        for (int mt = 0; mt < 4; ++mt) {
            const int r = mt * 16 + l16, rs = r & 7;
            half8 k0 = *(const half8*)&Ks[r][(quad ^ rs) * 8];
            half8 k1 = *(const half8*)&Ks[r][((quad + 4) ^ rs) * 8];
            f32x4 z = {0.f, 0.f, 0.f, 0.f};
            z = __builtin_amdgcn_mfma_f32_16x16x32_f16(k0, qa0, z, 0, 0, 0);   // swapped
            z = __builtin_amdgcn_mfma_f32_16x16x32_f16(k1, qa1, z, 0, 0, 0);
            S[mt] = z;
        }

        // p = bit ? exp2(S) : 0 ; pack pairs and write Ps[q=l16][m] (b64s)
        const unsigned losh = bmv.x >> (quad * 4);
        const unsigned hish = bmv.y >> (quad * 4);
        #pragma unroll
        for (int mt = 0; mt < 4; ++mt) {
            const unsigned wb = (mt < 2) ? losh : hish;
            const int sh = (mt & 1) * 16;
            const float p0 = ((wb >> (sh + 0)) & 1u) ? __builtin_exp2f(S[mt][0]) : 0.f;
            const float p1 = ((wb >> (sh + 1)) & 1u) ? __builtin_exp2f(S[mt][1]) : 0.f;
            const float p2 = ((wb >> (sh + 2)) & 1u) ? __builtin_exp2f(S[mt][2]) : 0.f;
            const float p3 = ((wb >> (sh + 3)) & 1u) ? __builtin_exp2f(S[mt][3]) : 0.f;
            psum += (p0 + p1) + (p2 + p3);
            const half2v lo2 = __builtin_bit_cast(half2v, __builtin_amdgcn_cvt_pkrtz(p0, p1));
            const half2v hi2 = __builtin_bit_cast(half2v, __builtin_amdgcn_cvt_pkrtz(p2, p3));
            half4v pv;
            pv[0] = lo2[0]; pv[1] = lo2[1]; pv[2] = hi2[0]; pv[3] = hi2[1];
            *(half4v*)&Ps[w][l16][mt * 16 + quad * 4] = pv;
        }
        __asm__ volatile("s_waitcnt lgkmcnt(0)" ::: "memory");
        half8 pa0 = *(const half8*)&Ps[w][l16][quad * 8];
        half8 pa1 = *(const half8*)&Ps[w][l16][32 + quad * 8];

        #pragma unroll
        for (int dt = 0; dt < 4; ++dt) {
            const int r = dt * 16 + l16, rs = r & 7;
            half8 v0 = *(const half8*)&Vs[r][(quad ^ rs) * 8];
            half8 v1 = *(const half8*)&Vs[r][((quad + 4) ^ rs) * 8];
            O[dt] = __builtin_amdgcn_mfma_f32_16x16x32_f16(pa0, v0, O[dt], 0, 0, 0);
            O[dt] = __builtin_amdgcn_mfma_f32_16x16x32_f16(pa1, v1, O[dt], 0, 0, 0);
        }

        if (it < (Mm / 4) / 64 - 1) {
            __syncthreads();
            stage_write();
            __syncthreads();
        }
    }

    // L[q]: sum across the 4 quads holding q=l16's m-chunks
    psum += __shfl_xor(psum, 16);
    psum += __shfl_xor(psum, 32);

    _Float16* op = Odst + ((size_t)b * Nn + n0 + w * 16 + quad * 4) * 256 + h * 64 + l16;
    #pragma unroll
    for (int reg = 0; reg < 4; ++reg)
        #pragma unroll
        for (int dt = 0; dt < 4; ++dt)
            op[(size_t)reg * 256 + dt * 16] = (_Float16)(O[dt][reg] * 0.0625f);
    if (lane < 16)
        Ldst[((size_t)b * Nn + n0 + w * 16 + l16) * 4 + h] = psum * 0.0625f;
}

// ---------------------------------------------------------------------------
// msg-projection with 4-way combine fused into A-staging (R8 version,
// reg-staged, issue-early/write-late). K=256, out -> Yp cols 256..511.
// Grid (64, 4).
// ---------------------------------------------------------------------------
__global__ __launch_bounds__(256)
void gemm_msg_kernel(const _Float16* __restrict__ Oa, const _Float16* __restrict__ Ob,
                     const _Float16* __restrict__ Oc, const _Float16* __restrict__ Od,
                     const float* __restrict__ La, const float* __restrict__ Lb,
                     const float* __restrict__ Lc, const float* __restrict__ Ld,
                     const _Float16* __restrict__ W, const float* __restrict__ bias,
                     _Float16* __restrict__ dst) {
    __shared__ __align__(16) _Float16 As[2 * 128 * 64];   // 32 KB
    __shared__ __align__(16) _Float16 Bs[2 * 64 * 64];    // 16 KB

    const int t = threadIdx.x;
    const int w = t >> 6, lane = t & 63, quad = lane >> 4, l16 = lane & 15;
    const int n0 = blockIdx.x * 128;
    const int og0 = blockIdx.y * 64;
    const int srow = t >> 3, sslot = t & 7;
    const int schunk = sslot ^ (srow & 7);
    constexpr int K = 256;

    f32x4 acc[2][4] = {};

    half8 oa[4], ob[4], oc[4], od[4];
    float inv[4];

    auto loadA = [&](int k0) {
        const int h = k0 >> 6;
        #pragma unroll
        for (int c = 0; c < 4; ++c) {
            const size_t row = (size_t)(n0 + c * 32 + srow);
            const size_t off = row * 256 + k0 + schunk * 8;
            oa[c] = *(const half8*)(Oa + off);
            ob[c] = *(const half8*)(Ob + off);
            oc[c] = *(const half8*)(Oc + off);
            od[c] = *(const half8*)(Od + off);
            inv[c] = 1.0f / (La[row * 4 + h] + Lb[row * 4 + h]
                           + Lc[row * 4 + h] + Ld[row * 4 + h]);
        }
    };
    auto writeA = [&](int nb) {
        #pragma unroll
        for (int c = 0; c < 4; ++c) {
            half8 m;
            #pragma unroll
            for (int k = 0; k < 8; ++k)
                m[k] = (_Float16)((((float)oa[c][k] + (float)ob[c][k])
                                 + ((float)oc[c][k] + (float)od[c][k])) * inv[c]);
            *(half8*)&As[nb * 8192 + c * 2048 + t * 8] = m;
        }
    };
    auto loadB = [&](int k0, int nb) {
        #pragma unroll
        for (int c = 0; c < 2; ++c)
            gload16(W + (size_t)(og0 + c * 32 + srow) * K + k0 + schunk * 8,
                    Bs + nb * 4096 + c * 2048 + t * 8);
    };

    loadA(0);
    loadB(0, 0);
    writeA(0);
    __asm__ volatile("s_waitcnt vmcnt(0)" ::: "memory");
    __syncthreads();

    int buf = 0;
    #pragma unroll 1
    for (int kt = 0; kt < 4; ++kt) {
        if (kt < 3) {
            loadA((kt + 1) * 64);
            loadB((kt + 1) * 64, buf ^ 1);
        }
        #pragma unroll
        for (int ks = 0; ks < 2; ++ks) {
            const int csw = ((ks * 4 + quad) ^ (l16 & 7)) * 8;
            half8 af[2], bf[4];
            #pragma unroll
            for (int i = 0; i < 2; ++i)
                af[i] = *(const half8*)&As[buf * 8192 + (w * 32 + i * 16 + l16) * 64 + csw];
            #pragma unroll
            for (int j = 0; j < 4; ++j)
                bf[j] = *(const half8*)&Bs[buf * 4096 + (j * 16 + l16) * 64 + csw];
            #pragma unroll
            for (int i = 0; i < 2; ++i)
                #pragma unroll
                for (int j = 0; j < 4; ++j)
                    acc[i][j] = __builtin_amdgcn_mfma_f32_16x16x32_f16(af[i], bf[j], acc[i][j], 0, 0, 0);
        }
        if (kt < 3) {
            writeA(buf ^ 1);
            __asm__ volatile("s_waitcnt vmcnt(0)" ::: "memory");
            __syncthreads();
            buf ^= 1;
        }
    }

    float bcol[4];
    #pragma unroll
    for (int j = 0; j < 4; ++j) bcol[j] = bias[og0 + j * 16 + l16];

    _Float16* Escr = As + w * 2048;
    #pragma unroll
    for (int i = 0; i < 2; ++i) {
        #pragma unroll
        for (int j = 0; j < 4; ++j)
            #pragma unroll
            for (int reg = 0; reg < 4; ++reg)
                Escr[(quad * 4 + reg) * 72 + j * 16 + l16] =
                    (_Float16)(acc[i][j][reg] + bcol[j]);
        __asm__ volatile("s_waitcnt lgkmcnt(0)" ::: "memory");
        const int row = lane & 15, oseg = (lane >> 4) * 16;
        half8 e0 = *(const half8*)&Escr[row * 72 + oseg];
        half8 e1 = *(const half8*)&Escr[row * 72 + oseg + 8];
        _Float16* dp = dst + (size_t)(n0 + w * 32 + i * 16 + row) * 512 + og0 + oseg;
        *(half8*)dp = e0;
        *(half8*)(dp + 8) = e1;
        __asm__ volatile("s_waitcnt lgkmcnt(0)" ::: "memory");
    }
}

// ---------------------------------------------------------------------------
extern "C" void kernel_launch(void* const* d_in, const int* in_sizes, int n_in,
                              void* d_out, int out_size, void* d_ws, size_t ws_size,
                              hipStream_t stream) {
    const float* x      = (const float*)d_in[0];
    const float* source = (const float*)d_in[1];
    const float* mask   = (const float*)d_in[2];
    const float* Wq = (const float*)d_in[3];
    const float* bq = (const float*)d_in[4];
    const float* Wk = (const float*)d_in[5];
    const float* bk = (const float*)d_in[6];
    const float* Wv = (const float*)d_in[7];
    const float* bv = (const float*)d_in[8];
    const float* Wm = (const float*)d_in[9];
    const float* bm = (const float*)d_in[10];
    const float* W1 = (const float*)d_in[11];
    const float* b1 = (const float*)d_in[12];
    const float* gamma = (const float*)d_in[13];
    const float* beta  = (const float*)d_in[14];
    const float* rmean = (const float*)d_in[15];
    const float* rvar  = (const float*)d_in[16];
    const float* W2 = (const float*)d_in[17];
    const float* b2 = (const float*)d_in[18];
    float* outp = (float*)d_out;

    // workspace layout (bytes)
    char* wsb = (char*)d_ws;
    _Float16* Yp   = (_Float16*)wsb;                       // [8192][512]  8 MB
    _Float16* Sp   = (_Float16*)(wsb + (8u << 20));        // [8192][256]  4 MB (-> O_C after qkv)
    _Float16* Qp   = (_Float16*)(wsb + (12u << 20));       // [8192][256]  4 MB
    _Float16* Kp   = (_Float16*)(wsb + (16u << 20));       // [8192][256]  4 MB
    _Float16* Vt   = (_Float16*)(wsb + (20u << 20));       // [1024][2048] 4 MB
    _Float16* Oa   = (_Float16*)(wsb + (24u << 20));       // [8192][256]  4 MB (O_A)
    _Float16* Hp   = (_Float16*)(wsb + (28u << 20));       // [8192][512]  8 MB (mlp1 out)
    // transients (dead before mlp1 writes Hp):
    unsigned long long* bmask = (unsigned long long*)(wsb + (28u << 20));  // 2 MB
    _Float16* Ob = (_Float16*)(wsb + (30u << 20));                          // 4 MB (O_B)
    float* La = (float*)(wsb + (34u << 20));                                // 128 KB
    float* Lb = (float*)(wsb + (34u << 20) + (128u << 10));                 // 128 KB
    float* Lc = (float*)(wsb + (34u << 20) + (256u << 10));                 // 128 KB
    float* Ld = (float*)(wsb + (34u << 20) + (384u << 10));                 // 128 KB
    _Float16* Oc = Sp;                       // Sp dead after qkv
    _Float16* Od = (_Float16*)outp;          // d_out dead until mlp2 writes it
    char* wp = wsb + (36u << 20);
    _Float16* Wqp  = (_Float16*)wp;            wp += 256 * 256 * 2;
    _Float16* Wkvp = (_Float16*)wp;            wp += 512 * 256 * 2;
    _Float16* Wmp  = (_Float16*)wp;            wp += 256 * 256 * 2;
    _Float16* W1p  = (_Float16*)wp;            wp += 512 * 512 * 2;
    _Float16* W2p  = (_Float16*)wp;            wp += 256 * 512 * 2;
    float* bqp  = (float*)wp;                  wp += 256 * 4;
    float* bkvp = (float*)wp;                  wp += 512 * 4;
    float* b1f  = (float*)wp;                  wp += 512 * 4;

    prep_all_kernel<<<4864, 256, 0, stream>>>(
        Wq, bq, Wk, bk, Wv, bv, Wm, W1, b1, gamma, beta, rmean, rvar, W2, mask,
        x, source, Wqp, bqp, Wkvp, bkvp, Wmp, W1p, b1f, W2p, bmask, Yp, Sp);

    // fused Q/K/V projection: (64, 12) blocks of 128x64.
    // Q pre-scaled by 0.125*log2(e) so attn softmax is a bare v_exp_f32.
    gemm4w_kernel<<<dim3(NT / 128, 12), 256, 0, stream>>>(
        Yp, Sp, Wqp, bqp, Qp, Kp, Vt, nullptr, 256, 512, 256, 3, 0, 0.18033688011f);

    attn_mfma_kernel<<<1024, 512, 0, stream>>>(Qp, Kp, Vt,
                                               (const unsigned int*)bmask,
                                               Oa, Ob, Oc, Od, La, Lb, Lc, Ld);

    // combine + msg projection fused: out -> Yp cols 256..511
    gemm_msg_kernel<<<dim3(NT / 128, 4), 256, 0, stream>>>(
        Oa, Ob, Oc, Od, La, Lb, Lc, Ld, Wmp, bm, Yp + 256);

    // MLP layer 1 (BN-folded, relu): A=Yp [n][512], out Hp [n][512]
    gemm4w_kernel<<<dim3(NT / 128, 8), 256, 0, stream>>>(
        Yp, nullptr, W1p, b1f, Hp, nullptr, nullptr, nullptr, 512, 512, 512, 0, 1, 1.0f);
    // MLP layer 2: A=Hp, fp32 out [b][256][n]
    gemm4w_kernel<<<dim3(NT / 128, 4), 256, 0, stream>>>(
        Hp, nullptr, W2p, b2, nullptr, nullptr, nullptr, outp, 512, 512, 0, 2, 0, 1.0f);
}

// Round 12
// 237.897 us; speedup vs baseline: 1.0986x; 1.0986x over previous
//
#include <hip/hip_runtime.h>

// Problem constants
constexpr int Bb = 4;     // batch
constexpr int Dd = 256;   // channels
constexpr int Nn = 2048;  // query positions
constexpr int Mm = 2048;  // source positions
constexpr int Hh = 4;     // heads
constexpr int D2 = 512;   // 2*D
constexpr int NT = Bb * Nn;  // 8192 total positions

#define FMAXV 3.402823466e38f

typedef _Float16 half8 __attribute__((ext_vector_type(8)));
typedef _Float16 half4v __attribute__((ext_vector_type(4)));
typedef _Float16 half2v __attribute__((ext_vector_type(2)));
typedef float f32x4 __attribute__((ext_vector_type(4)));

typedef const __attribute__((address_space(1))) void* gas_p;
typedef __attribute__((address_space(3))) void* las_p;

__device__ __forceinline__ void gload16(const void* g, void* l) {
    __builtin_amdgcn_global_load_lds((gas_p)g, (las_p)l, 16, 0, 0);
}

// ---------------------------------------------------------------------------
// Fused prepack: weights + bitmask + activation transpose (unchanged)
// ---------------------------------------------------------------------------
__global__ __launch_bounds__(256)
void prep_all_kernel(const float* __restrict__ Wq, const float* __restrict__ bq,
                     const float* __restrict__ Wk, const float* __restrict__ bk,
                     const float* __restrict__ Wv, const float* __restrict__ bv,
                     const float* __restrict__ Wm,
                     const float* __restrict__ W1, const float* __restrict__ b1,
                     const float* __restrict__ gamma, const float* __restrict__ beta,
                     const float* __restrict__ rmean, const float* __restrict__ rvar,
                     const float* __restrict__ W2, const float* __restrict__ mask,
                     const float* __restrict__ x, const float* __restrict__ source,
                     _Float16* __restrict__ Wqp, float* __restrict__ bqp,
                     _Float16* __restrict__ Wkvp, float* __restrict__ bkvp,
                     _Float16* __restrict__ Wmp,
                     _Float16* __restrict__ W1p, float* __restrict__ b1f,
                     _Float16* __restrict__ W2p,
                     unsigned long long* __restrict__ bmask,
                     _Float16* __restrict__ Yp, _Float16* __restrict__ Sp) {
    const int r = blockIdx.x, t = threadIdx.x;
    if (r < 256) {
        const int h = r >> 6, d = r & 63, so = d * Hh + h;
        Wqp[r * 256 + t] = (_Float16)Wq[so * 256 + t];
        if (t == 0) bqp[r] = bq[so];
    } else if (r < 768) {
        const int rr = r - 256, part = rr >> 8, o = rr & 255;
        const int h = o >> 6, d = o & 63, so = d * Hh + h;
        const float* Ws = part ? Wv : Wk;
        const float* bs = part ? bv : bk;
        Wkvp[rr * 256 + t] = (_Float16)Ws[so * 256 + t];
        if (t == 0) bkvp[rr] = bs[so];
    } else if (r < 1024) {
        const int o = r - 768;
        const int h = t >> 6, d = t & 63, sk = d * Hh + h;
        Wmp[o * 256 + t] = (_Float16)Wm[o * 256 + sk];
    } else if (r < 1536) {
        const int o = r - 1024;
        const float s = gamma[o] * rsqrtf(rvar[o] + 1e-3f);
        W1p[o * 512 + t]       = (_Float16)(W1[o * 512 + t] * s);
        W1p[o * 512 + t + 256] = (_Float16)(W1[o * 512 + t + 256] * s);
        if (t == 0) b1f[o] = (b1[o] - rmean[o]) * s + beta[o];
    } else if (r < 1792) {
        const int o = r - 1536;
        W2p[o * 512 + t]       = (_Float16)W2[o * 512 + t];
        W2p[o * 512 + t + 256] = (_Float16)W2[o * 512 + t + 256];
    } else if (r < 3840) {
        const int id = r - 1792;               // 0..2047
        const int w = t >> 6, lane = t & 63;
        const int row = id * 4 + w;            // 0..8191
        const float* mrow = mask + (size_t)row * Mm;
        unsigned long long* brow = bmask + (size_t)row * (Mm / 64);
        #pragma unroll 4
        for (int word = 0; word < Mm / 64; ++word) {
            const float v = mrow[word * 64 + lane];
            const unsigned long long bits = __ballot(v > 0.f);
            if (lane == 0) brow[word] = bits;
        }
    } else {
        __shared__ _Float16 Ts[64][72];
        const int px = r - 3840;
        const int n0 = (px & 31) * 64, c0 = ((px >> 5) & 3) * 64;
        const int z = px >> 7, b = z >> 1, which = z & 1;
        const float* src = which ? source : x;
        _Float16* dst = which ? Sp : Yp;
        const int stride = which ? 256 : 512;
        const int cl = t >> 2, np = (t & 3) * 16;
        const float* sp = src + ((size_t)b * Dd + c0 + cl) * Nn + n0 + np;
        #pragma unroll
        for (int i = 0; i < 4; ++i) {
            float4 v = *(const float4*)(sp + i * 4);
            Ts[np + i * 4 + 0][cl] = (_Float16)v.x;
            Ts[np + i * 4 + 1][cl] = (_Float16)v.y;
            Ts[np + i * 4 + 2][cl] = (_Float16)v.z;
            Ts[np + i * 4 + 3][cl] = (_Float16)v.w;
        }
        __syncthreads();
        const int nl = t >> 2, cp = (t & 3) * 16;
        half8 a0 = *(const half8*)&Ts[nl][cp];
        half8 a1 = *(const half8*)&Ts[nl][cp + 8];
        _Float16* dp = dst + ((size_t)b * Nn + n0 + nl) * stride + c0 + cp;
        *(half8*)dp = a0;
        *(half8*)(dp + 8) = a1;
    }
}

// ---------------------------------------------------------------------------
// GEMM (R7 structure, unchanged): BM=128 BN=64, gload_lds staging + XOR
// swizzle, LDS 48 KB, coalesced transpose epilogues for V / fp32 out.
// ---------------------------------------------------------------------------
__global__ __launch_bounds__(256)
void gemm4w_kernel(const _Float16* __restrict__ A, const _Float16* __restrict__ A2,
                   const _Float16* __restrict__ W, const float* __restrict__ bias,
                   _Float16* __restrict__ dst0, _Float16* __restrict__ dst1,
                   _Float16* __restrict__ dst2, float* __restrict__ dstF,
                   int K, int sA, int sOut, int modeSel, int relu, float oscale) {
    __shared__ __align__(16) _Float16 As[2 * 128 * 64];   // 32 KB
    __shared__ __align__(16) _Float16 Bs[2 * 64 * 64];    // 16 KB

    const int t = threadIdx.x;
    const int w = t >> 6, lane = t & 63, quad = lane >> 4, l16 = lane & 15;
    const int n0 = blockIdx.x * 128;
    const int og0 = blockIdx.y * 64;

    int mode = 0, oloc0 = og0;
    const _Float16* Ab = A;
    int sAl = sA;
    _Float16* d0 = dst0;
    float osc = oscale;
    if (modeSel == 3) {
        const int part = blockIdx.y >> 2;               // 0=Q, 1=K, 2=V
        if (part == 1)      { Ab = A2; sAl = 256; d0 = dst1; oloc0 = og0 - 256; osc = 1.0f; }
        else if (part == 2) { Ab = A2; sAl = 256; mode = 1; oloc0 = og0 - 512; osc = 1.0f; }
    } else if (modeSel == 2) {
        mode = 2;
    }

    const int srow = t >> 3, sslot = t & 7;
    const int schunk = sslot ^ (srow & 7);

    f32x4 acc[2][4] = {};
    const int nk = K / 64;
    int buf = 0;

    {
        #pragma unroll
        for (int c = 0; c < 4; ++c)
            gload16(Ab + (size_t)(n0 + c * 32 + srow) * sAl + schunk * 8,
                    As + c * 2048 + t * 8);
        #pragma unroll
        for (int c = 0; c < 2; ++c)
            gload16(W + (size_t)(og0 + c * 32 + srow) * K + schunk * 8,
                    Bs + c * 2048 + t * 8);
        __asm__ volatile("s_waitcnt vmcnt(0)" ::: "memory");
        __syncthreads();
    }

    #pragma unroll 1
    for (int kt = 0; kt < nk; ++kt) {
        if (kt + 1 < nk) {
            const int k0 = (kt + 1) * 64, nb = buf ^ 1;
            #pragma unroll
            for (int c = 0; c < 4; ++c)
                gload16(Ab + (size_t)(n0 + c * 32 + srow) * sAl + k0 + schunk * 8,
                        As + nb * 8192 + c * 2048 + t * 8);
            #pragma unroll
            for (int c = 0; c < 2; ++c)
                gload16(W + (size_t)(og0 + c * 32 + srow) * K + k0 + schunk * 8,
                        Bs + nb * 4096 + c * 2048 + t * 8);
        }
        #pragma unroll
        for (int ks = 0; ks < 2; ++ks) {
            const int csw = ((ks * 4 + quad) ^ (l16 & 7)) * 8;
            half8 af[2], bf[4];
            #pragma unroll
            for (int i = 0; i < 2; ++i)
                af[i] = *(const half8*)&As[buf * 8192 + (w * 32 + i * 16 + l16) * 64 + csw];
            #pragma unroll
            for (int j = 0; j < 4; ++j)
                bf[j] = *(const half8*)&Bs[buf * 4096 + (j * 16 + l16) * 64 + csw];
            #pragma unroll
            for (int i = 0; i < 2; ++i)
                #pragma unroll
                for (int j = 0; j < 4; ++j)
                    acc[i][j] = __builtin_amdgcn_mfma_f32_16x16x32_f16(af[i], bf[j], acc[i][j], 0, 0, 0);
        }
        if (kt + 1 < nk) {
            __asm__ volatile("s_waitcnt vmcnt(0)" ::: "memory");
            __syncthreads();
            buf ^= 1;
        }
    }

    float bcol[4];
    #pragma unroll
    for (int j = 0; j < 4; ++j) bcol[j] = bias[og0 + j * 16 + l16];

    if (mode == 0) {
        _Float16* Escr = As + w * 2048;
        #pragma unroll
        for (int i = 0; i < 2; ++i) {
            #pragma unroll
            for (int j = 0; j < 4; ++j)
                #pragma unroll
                for (int reg = 0; reg < 4; ++reg) {
                    float v = (acc[i][j][reg] + bcol[j]) * osc;
                    if (relu) v = fmaxf(v, 0.f);
                    Escr[(quad * 4 + reg) * 72 + j * 16 + l16] = (_Float16)v;
                }
            __asm__ volatile("s_waitcnt lgkmcnt(0)" ::: "memory");
            const int row = lane & 15, oseg = (lane >> 4) * 16;
            half8 e0 = *(const half8*)&Escr[row * 72 + oseg];
            half8 e1 = *(const half8*)&Escr[row * 72 + oseg + 8];
            _Float16* dp = d0 + (size_t)(n0 + w * 32 + i * 16 + row) * sOut + oloc0 + oseg;
            *(half8*)dp = e0;
            *(half8*)(dp + 8) = e1;
            __asm__ volatile("s_waitcnt lgkmcnt(0)" ::: "memory");
        }
    } else if (mode == 1) {
        #pragma unroll
        for (int i = 0; i < 2; ++i)
            #pragma unroll
            for (int j = 0; j < 4; ++j) {
                const int c = j * 16 + l16;
                const int mloc = w * 32 + i * 16 + quad * 4;
                const int sw = l16 * 8;
                half4v pv;
                #pragma unroll
                for (int reg = 0; reg < 4; ++reg)
                    pv[reg] = (_Float16)(acc[i][j][reg] + bcol[j]);
                *(half4v*)&As[c * 128 + (mloc ^ sw)] = pv;
            }
        __syncthreads();
        const int n0m = n0 & 2047, bidx = n0 >> 11;
        #pragma unroll
        for (int r = 0; r < 2; ++r) {
            const int c = (t >> 3) + r * 32;
            const int mch = (t & 7) * 16;
            const int sw = (c & 15) * 8;
            half8 v0 = *(const half8*)&As[c * 128 + (mch ^ sw)];
            half8 v1 = *(const half8*)&As[c * 128 + ((mch + 8) ^ sw)];
            _Float16* dp = dst2 + ((size_t)bidx * 256 + oloc0 + c) * (size_t)Mm + n0m + mch;
            *(half8*)dp = v0;
            *(half8*)(dp + 8) = v1;
        }
    } else {
        __syncthreads();
        float* scr = (float*)As;
        #pragma unroll
        for (int i = 0; i < 2; ++i)
            #pragma unroll
            for (int j = 0; j < 4; ++j) {
                const int c = j * 16 + l16;
                const int mloc = w * 32 + i * 16 + quad * 4;
                const int sw = (c & 7) * 4;
                f32x4 v;
                #pragma unroll
                for (int reg = 0; reg < 4; ++reg) v[reg] = acc[i][j][reg] + bcol[j];
                *(f32x4*)&scr[c * 128 + (mloc ^ sw)] = v;
            }
        __syncthreads();
        const int n0m = n0 & 2047, bidx = n0 >> 11;
        #pragma unroll
        for (int r = 0; r < 2; ++r) {
            const int c = (t >> 3) + r * 32;
            const int mch = (t & 7) * 16;
            const int sw = (c & 7) * 4;
            float* dp = dstF + ((size_t)bidx * 256 + og0 + c) * (size_t)Nn + n0m + mch;
            #pragma unroll
            for (int k = 0; k < 4; ++k)
                *(f32x4*)(dp + k * 4) = *(const f32x4*)&scr[c * 128 + ((mch + k * 4) ^ sw)];
        }
    }
}

// ---------------------------------------------------------------------------
// MFMA attention R12: R11's 8-wave full-occupancy structure, de-poisoned.
// R11 evidence: occupancy 29->66% worked, but launch_bounds(512,8) forced a
// 64-VGPR budget -> compiler capped 32 arch VGPRs + SPILLED (WRITE_SIZE
// 8.7->155 MB = scratch traffic; attn 44->72us HBM-bound at 2.8 TB/s).
// Fixes: (1) launch_bounds(512) only -> natural ~64-72 VGPR, no spill,
// 3-4 blocks/CU = 24-32 waves/CU; (2) dense O-store: stage O through the
// per-wave Ps slice (free after last PV) -> 16B/lane coalesced 128B/row
// stores instead of 32B sectors. Internals otherwise = R10/R11.
// Grid 1024 (XCD-aware), 512 thr, LDS 34.8 KB.
// ---------------------------------------------------------------------------
__global__ __launch_bounds__(512)
void attn_mfma_kernel(const _Float16* __restrict__ Qp, const _Float16* __restrict__ Kp,
                      const _Float16* __restrict__ Vt,
                      const unsigned int* __restrict__ bmask,
                      _Float16* __restrict__ Oa, _Float16* __restrict__ Ob,
                      _Float16* __restrict__ Oc, _Float16* __restrict__ Od,
                      float* __restrict__ La, float* __restrict__ Lb,
                      float* __restrict__ Lc, float* __restrict__ Ld) {
    __shared__ __align__(16) _Float16 Ks[64][64];      // 8192 B, swizzled
    __shared__ __align__(16) _Float16 Vs[64][64];      // 8192 B, swizzled
    __shared__ __align__(16) _Float16 Ps[8][16][72];   // 18432 B

    // XCD-aware decomposition: id%8 = XCD slot -> bh pair
    const int id = blockIdx.x;
    const int xcd = id & 7, loc = id >> 3;             // loc 0..127
    const int bh = xcd * 2 + (loc >> 6);               // 0..15
    const int sub = loc & 63;
    const int mquart = sub & 3;
    const int n0 = (sub >> 2) * 128;                   // 16 tiles of 128 rows
    const int b = bh >> 2, h = bh & 3;

    const int t = threadIdx.x;
    const int w = t >> 6, lane = t & 63, quad = lane >> 4, l16 = lane & 15;

    const _Float16* qp = Qp + ((size_t)b * Nn + n0 + w * 16 + l16) * 256 + h * 64 + quad * 8;
    const half8 qa0 = *(const half8*)(qp);
    const half8 qa1 = *(const half8*)(qp + 32);

    const _Float16* Kstg = Kp + (size_t)b * Nn * 256 + h * 64;
    const _Float16* Vstg = Vt + ((size_t)b * 256 + h * 64) * (size_t)Mm;
    // staging: 512 threads, each one 16B chunk of K and of V.
    const int sr = t >> 3;                             // row 0..63
    const int sl = t & 7;                              // 16B slot 0..7
    const int ss = sl ^ (sr & 7);                      // swizzled slot

    // per-lane bitmask row: q = n0 + w*16 + l16
    const unsigned int* bmRow = bmask + ((size_t)b * Nn + n0 + w * 16 + l16) * (Mm / 32);

    _Float16* Odst = mquart == 0 ? Oa : mquart == 1 ? Ob : mquart == 2 ? Oc : Od;
    float*    Ldst = mquart == 0 ? La : mquart == 1 ? Lb : mquart == 2 ? Lc : Ld;
    const int mbeg = mquart * (Mm / 4);

    float psum = 0.f;
    f32x4 O[4] = {};

    half8 sk, sv;
    auto stage_load = [&](int m0) {
        sk = *(const half8*)(Kstg + (size_t)(m0 + sr) * 256 + sl * 8);
        sv = *(const half8*)(Vstg + (size_t)sr * Mm + m0 + sl * 8);
    };
    auto stage_write = [&]() {
        *(half8*)&Ks[sr][ss * 8] = sk;
        *(half8*)&Vs[sr][ss * 8] = sv;
    };

    stage_load(mbeg);
    stage_write();
    __syncthreads();

    #pragma unroll 1
    for (int it = 0; it < (Mm / 4) / 64; ++it) {
        const int m0 = mbeg + it * 64;
        if (it < (Mm / 4) / 64 - 1) stage_load(m0 + 64);

        const uint2 bmv = *(const uint2*)(bmRow + (m0 >> 5));

        f32x4 S[4];
        #pragma unroll
        for (int mt = 0; mt < 4; ++mt) {
            const int r = mt * 16 + l16, rs = r & 7;
            half8 k0 = *(const half8*)&Ks[r][(quad ^ rs) * 8];
            half8 k1 = *(const half8*)&Ks[r][((quad + 4) ^ rs) * 8];
            f32x4 z = {0.f, 0.f, 0.f, 0.f};
            z = __builtin_amdgcn_mfma_f32_16x16x32_f16(k0, qa0, z, 0, 0, 0);   // swapped
            z = __builtin_amdgcn_mfma_f32_16x16x32_f16(k1, qa1, z, 0, 0, 0);
            S[mt] = z;
        }

        // p = bit ? exp2(S) : 0 ; pack pairs and write Ps[q=l16][m] (b64s)
        const unsigned losh = bmv.x >> (quad * 4);
        const unsigned hish = bmv.y >> (quad * 4);
        #pragma unroll
        for (int mt = 0; mt < 4; ++mt) {
            const unsigned wb = (mt < 2) ? losh : hish;
            const int sh = (mt & 1) * 16;
            const float p0 = ((wb >> (sh + 0)) & 1u) ? __builtin_exp2f(S[mt][0]) : 0.f;
            const float p1 = ((wb >> (sh + 1)) & 1u) ? __builtin_exp2f(S[mt][1]) : 0.f;
            const float p2 = ((wb >> (sh + 2)) & 1u) ? __builtin_exp2f(S[mt][2]) : 0.f;
            const float p3 = ((wb >> (sh + 3)) & 1u) ? __builtin_exp2f(S[mt][3]) : 0.f;
            psum += (p0 + p1) + (p2 + p3);
            const half2v lo2 = __builtin_bit_cast(half2v, __builtin_amdgcn_cvt_pkrtz(p0, p1));
            const half2v hi2 = __builtin_bit_cast(half2v, __builtin_amdgcn_cvt_pkrtz(p2, p3));
            half4v pv;
            pv[0] = lo2[0]; pv[1] = lo2[1]; pv[2] = hi2[0]; pv[3] = hi2[1];
            *(half4v*)&Ps[w][l16][mt * 16 + quad * 4] = pv;
        }
        __asm__ volatile("s_waitcnt lgkmcnt(0)" ::: "memory");
        half8 pa0 = *(const half8*)&Ps[w][l16][quad * 8];
        half8 pa1 = *(const half8*)&Ps[w][l16][32 + quad * 8];

        #pragma unroll
        for (int dt = 0; dt < 4; ++dt) {
            const int r = dt * 16 + l16, rs = r & 7;
            half8 v0 = *(const half8*)&Vs[r][(quad ^ rs) * 8];
            half8 v1 = *(const half8*)&Vs[r][((quad + 4) ^ rs) * 8];
            O[dt] = __builtin_amdgcn_mfma_f32_16x16x32_f16(pa0, v0, O[dt], 0, 0, 0);
            O[dt] = __builtin_amdgcn_mfma_f32_16x16x32_f16(pa1, v1, O[dt], 0, 0, 0);
        }

        if (it < (Mm / 4) / 64 - 1) {
            __syncthreads();
            stage_write();
            __syncthreads();
        }
    }

    // L[q]: sum across the 4 quads holding q=l16's m-chunks
    psum += __shfl_xor(psum, 16);
    psum += __shfl_xor(psum, 32);

    // dense O-store: stage O in this wave's Ps slice (free after last PV),
    // then 16B/lane coalesced stores — full 128B per row, no 32B sectors.
    #pragma unroll
    for (int dt = 0; dt < 4; ++dt)
        #pragma unroll
        for (int reg = 0; reg < 4; ++reg)
            Ps[w][quad * 4 + reg][dt * 16 + l16] = (_Float16)(O[dt][reg] * 0.0625f);
    __asm__ volatile("s_waitcnt lgkmcnt(0)" ::: "memory");
    #pragma unroll
    for (int u2 = 0; u2 < 2; ++u2) {
        const int u = lane * 2 + u2;               // 0..127
        const int r = u >> 3, c = u & 7;           // row 0..15, 16B chunk 0..7
        half8 v = *(const half8*)&Ps[w][r][c * 8];
        *(half8*)(Odst + ((size_t)b * Nn + n0 + w * 16 + r) * 256 + h * 64 + c * 8) = v;
    }
    if (lane < 16)
        Ldst[((size_t)b * Nn + n0 + w * 16 + l16) * 4 + h] = psum * 0.0625f;
}

// ---------------------------------------------------------------------------
// msg-projection with 4-way combine fused into A-staging (reg-staged,
// issue-early/write-late). K=256, out -> Yp cols 256..511. Grid (64, 4).
// ---------------------------------------------------------------------------
__global__ __launch_bounds__(256)
void gemm_msg_kernel(const _Float16* __restrict__ Oa, const _Float16* __restrict__ Ob,
                     const _Float16* __restrict__ Oc, const _Float16* __restrict__ Od,
                     const float* __restrict__ La, const float* __restrict__ Lb,
                     const float* __restrict__ Lc, const float* __restrict__ Ld,
                     const _Float16* __restrict__ W, const float* __restrict__ bias,
                     _Float16* __restrict__ dst) {
    __shared__ __align__(16) _Float16 As[2 * 128 * 64];   // 32 KB
    __shared__ __align__(16) _Float16 Bs[2 * 64 * 64];    // 16 KB

    const int t = threadIdx.x;
    const int w = t >> 6, lane = t & 63, quad = lane >> 4, l16 = lane & 15;
    const int n0 = blockIdx.x * 128;
    const int og0 = blockIdx.y * 64;
    const int srow = t >> 3, sslot = t & 7;
    const int schunk = sslot ^ (srow & 7);
    constexpr int K = 256;

    f32x4 acc[2][4] = {};

    half8 oa[4], ob[4], oc[4], od[4];
    float inv[4];

    auto loadA = [&](int k0) {
        const int h = k0 >> 6;
        #pragma unroll
        for (int c = 0; c < 4; ++c) {
            const size_t row = (size_t)(n0 + c * 32 + srow);
            const size_t off = row * 256 + k0 + schunk * 8;
            oa[c] = *(const half8*)(Oa + off);
            ob[c] = *(const half8*)(Ob + off);
            oc[c] = *(const half8*)(Oc + off);
            od[c] = *(const half8*)(Od + off);
            inv[c] = 1.0f / (La[row * 4 + h] + Lb[row * 4 + h]
                           + Lc[row * 4 + h] + Ld[row * 4 + h]);
        }
    };
    auto writeA = [&](int nb) {
        #pragma unroll
        for (int c = 0; c < 4; ++c) {
            half8 m;
            #pragma unroll
            for (int k = 0; k < 8; ++k)
                m[k] = (_Float16)((((float)oa[c][k] + (float)ob[c][k])
                                 + ((float)oc[c][k] + (float)od[c][k])) * inv[c]);
            *(half8*)&As[nb * 8192 + c * 2048 + t * 8] = m;
        }
    };
    auto loadB = [&](int k0, int nb) {
        #pragma unroll
        for (int c = 0; c < 2; ++c)
            gload16(W + (size_t)(og0 + c * 32 + srow) * K + k0 + schunk * 8,
                    Bs + nb * 4096 + c * 2048 + t * 8);
    };

    loadA(0);
    loadB(0, 0);
    writeA(0);
    __asm__ volatile("s_waitcnt vmcnt(0)" ::: "memory");
    __syncthreads();

    int buf = 0;
    #pragma unroll 1
    for (int kt = 0; kt < 4; ++kt) {
        if (kt < 3) {
            loadA((kt + 1) * 64);
            loadB((kt + 1) * 64, buf ^ 1);
        }
        #pragma unroll
        for (int ks = 0; ks < 2; ++ks) {
            const int csw = ((ks * 4 + quad) ^ (l16 & 7)) * 8;
            half8 af[2], bf[4];
            #pragma unroll
            for (int i = 0; i < 2; ++i)
                af[i] = *(const half8*)&As[buf * 8192 + (w * 32 + i * 16 + l16) * 64 + csw];
            #pragma unroll
            for (int j = 0; j < 4; ++j)
                bf[j] = *(const half8*)&Bs[buf * 4096 + (j * 16 + l16) * 64 + csw];
            #pragma unroll
            for (int i = 0; i < 2; ++i)
                #pragma unroll
                for (int j = 0; j < 4; ++j)
                    acc[i][j] = __builtin_amdgcn_mfma_f32_16x16x32_f16(af[i], bf[j], acc[i][j], 0, 0, 0);
        }
        if (kt < 3) {
            writeA(buf ^ 1);
            __asm__ volatile("s_waitcnt vmcnt(0)" ::: "memory");
            __syncthreads();
            buf ^= 1;
        }
    }

    float bcol[4];
    #pragma unroll
    for (int j = 0; j < 4; ++j) bcol[j] = bias[og0 + j * 16 + l16];

    _Float16* Escr = As + w * 2048;
    #pragma unroll
    for (int i = 0; i < 2; ++i) {
        #pragma unroll
        for (int j = 0; j < 4; ++j)
            #pragma unroll
            for (int reg = 0; reg < 4; ++reg)
                Escr[(quad * 4 + reg) * 72 + j * 16 + l16] =
                    (_Float16)(acc[i][j][reg] + bcol[j]);
        __asm__ volatile("s_waitcnt lgkmcnt(0)" ::: "memory");
        const int row = lane & 15, oseg = (lane >> 4) * 16;
        half8 e0 = *(const half8*)&Escr[row * 72 + oseg];
        half8 e1 = *(const half8*)&Escr[row * 72 + oseg + 8];
        _Float16* dp = dst + (size_t)(n0 + w * 32 + i * 16 + row) * 512 + og0 + oseg;
        *(half8*)dp = e0;
        *(half8*)(dp + 8) = e1;
        __asm__ volatile("s_waitcnt lgkmcnt(0)" ::: "memory");
    }
}

// ---------------------------------------------------------------------------
extern "C" void kernel_launch(void* const* d_in, const int* in_sizes, int n_in,
                              void* d_out, int out_size, void* d_ws, size_t ws_size,
                              hipStream_t stream) {
    const float* x      = (const float*)d_in[0];
    const float* source = (const float*)d_in[1];
    const float* mask   = (const float*)d_in[2];
    const float* Wq = (const float*)d_in[3];
    const float* bq = (const float*)d_in[4];
    const float* Wk = (const float*)d_in[5];
    const float* bk = (const float*)d_in[6];
    const float* Wv = (const float*)d_in[7];
    const float* bv = (const float*)d_in[8];
    const float* Wm = (const float*)d_in[9];
    const float* bm = (const float*)d_in[10];
    const float* W1 = (const float*)d_in[11];
    const float* b1 = (const float*)d_in[12];
    const float* gamma = (const float*)d_in[13];
    const float* beta  = (const float*)d_in[14];
    const float* rmean = (const float*)d_in[15];
    const float* rvar  = (const float*)d_in[16];
    const float* W2 = (const float*)d_in[17];
    const float* b2 = (const float*)d_in[18];
    float* outp = (float*)d_out;

    // workspace layout (bytes)
    char* wsb = (char*)d_ws;
    _Float16* Yp   = (_Float16*)wsb;                       // [8192][512]  8 MB
    _Float16* Sp   = (_Float16*)(wsb + (8u << 20));        // [8192][256]  4 MB (-> O_C after qkv)
    _Float16* Qp   = (_Float16*)(wsb + (12u << 20));       // [8192][256]  4 MB
    _Float16* Kp   = (_Float16*)(wsb + (16u << 20));       // [8192][256]  4 MB
    _Float16* Vt   = (_Float16*)(wsb + (20u << 20));       // [1024][2048] 4 MB
    _Float16* Oa   = (_Float16*)(wsb + (24u << 20));       // [8192][256]  4 MB (O_A)
    _Float16* Hp   = (_Float16*)(wsb + (28u << 20));       // [8192][512]  8 MB (mlp1 out)
    // transients (dead before mlp1 writes Hp):
    unsigned long long* bmask = (unsigned long long*)(wsb + (28u << 20));  // 2 MB
    _Float16* Ob = (_Float16*)(wsb + (30u << 20));                          // 4 MB (O_B)
    float* La = (float*)(wsb + (34u << 20));                                // 128 KB
    float* Lb = (float*)(wsb + (34u << 20) + (128u << 10));                 // 128 KB
    float* Lc = (float*)(wsb + (34u << 20) + (256u << 10));                 // 128 KB
    float* Ld = (float*)(wsb + (34u << 20) + (384u << 10));                 // 128 KB
    _Float16* Oc = Sp;                       // Sp dead after qkv
    _Float16* Od = (_Float16*)outp;          // d_out dead until mlp2 writes it
    char* wp = wsb + (36u << 20);
    _Float16* Wqp  = (_Float16*)wp;            wp += 256 * 256 * 2;
    _Float16* Wkvp = (_Float16*)wp;            wp += 512 * 256 * 2;
    _Float16* Wmp  = (_Float16*)wp;            wp += 256 * 256 * 2;
    _Float16* W1p  = (_Float16*)wp;            wp += 512 * 512 * 2;
    _Float16* W2p  = (_Float16*)wp;            wp += 256 * 512 * 2;
    float* bqp  = (float*)wp;                  wp += 256 * 4;
    float* bkvp = (float*)wp;                  wp += 512 * 4;
    float* b1f  = (float*)wp;                  wp += 512 * 4;

    prep_all_kernel<<<4864, 256, 0, stream>>>(
        Wq, bq, Wk, bk, Wv, bv, Wm, W1, b1, gamma, beta, rmean, rvar, W2, mask,
        x, source, Wqp, bqp, Wkvp, bkvp, Wmp, W1p, b1f, W2p, bmask, Yp, Sp);

    // fused Q/K/V projection: (64, 12) blocks of 128x64.
    // Q pre-scaled by 0.125*log2(e) so attn softmax is a bare v_exp_f32.
    gemm4w_kernel<<<dim3(NT / 128, 12), 256, 0, stream>>>(
        Yp, Sp, Wqp, bqp, Qp, Kp, Vt, nullptr, 256, 512, 256, 3, 0, 0.18033688011f);

    attn_mfma_kernel<<<1024, 512, 0, stream>>>(Qp, Kp, Vt,
                                               (const unsigned int*)bmask,
                                               Oa, Ob, Oc, Od, La, Lb, Lc, Ld);

    // combine + msg projection fused: out -> Yp cols 256..511
    gemm_msg_kernel<<<dim3(NT / 128, 4), 256, 0, stream>>>(
        Oa, Ob, Oc, Od, La, Lb, Lc, Ld, Wmp, bm, Yp + 256);

    // MLP layer 1 (BN-folded, relu): A=Yp [n][512], out Hp [n][512]
    gemm4w_kernel<<<dim3(NT / 128, 8), 256, 0, stream>>>(
        Yp, nullptr, W1p, b1f, Hp, nullptr, nullptr, nullptr, 512, 512, 512, 0, 1, 1.0f);
    // MLP layer 2: A=Hp, fp32 out [b][256][n]
    gemm4w_kernel<<<dim3(NT / 128, 4), 256, 0, stream>>>(
        Hp, nullptr, W2p, b2, nullptr, nullptr, nullptr, outp, 512, 512, 0, 2, 0, 1.0f);
}

// Round 13
// 237.792 us; speedup vs baseline: 1.0991x; 1.0004x over previous
//
#include <hip/hip_runtime.h>

// Problem constants
constexpr int Bb = 4;     // batch
constexpr int Dd = 256;   // channels
constexpr int Nn = 2048;  // query positions
constexpr int Mm = 2048;  // source positions
constexpr int Hh = 4;     // heads
constexpr int D2 = 512;   // 2*D
constexpr int NT = Bb * Nn;  // 8192 total positions

#define FMAXV 3.402823466e38f

typedef _Float16 half8 __attribute__((ext_vector_type(8)));
typedef _Float16 half4v __attribute__((ext_vector_type(4)));
typedef _Float16 half2v __attribute__((ext_vector_type(2)));
typedef float f32x4 __attribute__((ext_vector_type(4)));

typedef const __attribute__((address_space(1))) void* gas_p;
typedef __attribute__((address_space(3))) void* las_p;

__device__ __forceinline__ void gload16(const void* g, void* l) {
    __builtin_amdgcn_global_load_lds((gas_p)g, (las_p)l, 16, 0, 0);
}

// ---------------------------------------------------------------------------
// Fused prepack: weights + bitmask + activation transpose (unchanged)
// ---------------------------------------------------------------------------
__global__ __launch_bounds__(256)
void prep_all_kernel(const float* __restrict__ Wq, const float* __restrict__ bq,
                     const float* __restrict__ Wk, const float* __restrict__ bk,
                     const float* __restrict__ Wv, const float* __restrict__ bv,
                     const float* __restrict__ Wm,
                     const float* __restrict__ W1, const float* __restrict__ b1,
                     const float* __restrict__ gamma, const float* __restrict__ beta,
                     const float* __restrict__ rmean, const float* __restrict__ rvar,
                     const float* __restrict__ W2, const float* __restrict__ mask,
                     const float* __restrict__ x, const float* __restrict__ source,
                     _Float16* __restrict__ Wqp, float* __restrict__ bqp,
                     _Float16* __restrict__ Wkvp, float* __restrict__ bkvp,
                     _Float16* __restrict__ Wmp,
                     _Float16* __restrict__ W1p, float* __restrict__ b1f,
                     _Float16* __restrict__ W2p,
                     unsigned long long* __restrict__ bmask,
                     _Float16* __restrict__ Yp, _Float16* __restrict__ Sp) {
    const int r = blockIdx.x, t = threadIdx.x;
    if (r < 256) {
        const int h = r >> 6, d = r & 63, so = d * Hh + h;
        Wqp[r * 256 + t] = (_Float16)Wq[so * 256 + t];
        if (t == 0) bqp[r] = bq[so];
    } else if (r < 768) {
        const int rr = r - 256, part = rr >> 8, o = rr & 255;
        const int h = o >> 6, d = o & 63, so = d * Hh + h;
        const float* Ws = part ? Wv : Wk;
        const float* bs = part ? bv : bk;
        Wkvp[rr * 256 + t] = (_Float16)Ws[so * 256 + t];
        if (t == 0) bkvp[rr] = bs[so];
    } else if (r < 1024) {
        const int o = r - 768;
        const int h = t >> 6, d = t & 63, sk = d * Hh + h;
        Wmp[o * 256 + t] = (_Float16)Wm[o * 256 + sk];
    } else if (r < 1536) {
        const int o = r - 1024;
        const float s = gamma[o] * rsqrtf(rvar[o] + 1e-3f);
        W1p[o * 512 + t]       = (_Float16)(W1[o * 512 + t] * s);
        W1p[o * 512 + t + 256] = (_Float16)(W1[o * 512 + t + 256] * s);
        if (t == 0) b1f[o] = (b1[o] - rmean[o]) * s + beta[o];
    } else if (r < 1792) {
        const int o = r - 1536;
        W2p[o * 512 + t]       = (_Float16)W2[o * 512 + t];
        W2p[o * 512 + t + 256] = (_Float16)W2[o * 512 + t + 256];
    } else if (r < 3840) {
        const int id = r - 1792;               // 0..2047
        const int w = t >> 6, lane = t & 63;
        const int row = id * 4 + w;            // 0..8191
        const float* mrow = mask + (size_t)row * Mm;
        unsigned long long* brow = bmask + (size_t)row * (Mm / 64);
        #pragma unroll 4
        for (int word = 0; word < Mm / 64; ++word) {
            const float v = mrow[word * 64 + lane];
            const unsigned long long bits = __ballot(v > 0.f);
            if (lane == 0) brow[word] = bits;
        }
    } else {
        __shared__ _Float16 Ts[64][72];
        const int px = r - 3840;
        const int n0 = (px & 31) * 64, c0 = ((px >> 5) & 3) * 64;
        const int z = px >> 7, b = z >> 1, which = z & 1;
        const float* src = which ? source : x;
        _Float16* dst = which ? Sp : Yp;
        const int stride = which ? 256 : 512;
        const int cl = t >> 2, np = (t & 3) * 16;
        const float* sp = src + ((size_t)b * Dd + c0 + cl) * Nn + n0 + np;
        #pragma unroll
        for (int i = 0; i < 4; ++i) {
            float4 v = *(const float4*)(sp + i * 4);
            Ts[np + i * 4 + 0][cl] = (_Float16)v.x;
            Ts[np + i * 4 + 1][cl] = (_Float16)v.y;
            Ts[np + i * 4 + 2][cl] = (_Float16)v.z;
            Ts[np + i * 4 + 3][cl] = (_Float16)v.w;
        }
        __syncthreads();
        const int nl = t >> 2, cp = (t & 3) * 16;
        half8 a0 = *(const half8*)&Ts[nl][cp];
        half8 a1 = *(const half8*)&Ts[nl][cp + 8];
        _Float16* dp = dst + ((size_t)b * Nn + n0 + nl) * stride + c0 + cp;
        *(half8*)dp = a0;
        *(half8*)(dp + 8) = a1;
    }
}

// ---------------------------------------------------------------------------
// GEMM (R7 structure, unchanged): BM=128 BN=64, gload_lds staging + XOR
// swizzle, LDS 48 KB, coalesced transpose epilogues for V / fp32 out.
// ---------------------------------------------------------------------------
__global__ __launch_bounds__(256)
void gemm4w_kernel(const _Float16* __restrict__ A, const _Float16* __restrict__ A2,
                   const _Float16* __restrict__ W, const float* __restrict__ bias,
                   _Float16* __restrict__ dst0, _Float16* __restrict__ dst1,
                   _Float16* __restrict__ dst2, float* __restrict__ dstF,
                   int K, int sA, int sOut, int modeSel, int relu, float oscale) {
    __shared__ __align__(16) _Float16 As[2 * 128 * 64];   // 32 KB
    __shared__ __align__(16) _Float16 Bs[2 * 64 * 64];    // 16 KB

    const int t = threadIdx.x;
    const int w = t >> 6, lane = t & 63, quad = lane >> 4, l16 = lane & 15;
    const int n0 = blockIdx.x * 128;
    const int og0 = blockIdx.y * 64;

    int mode = 0, oloc0 = og0;
    const _Float16* Ab = A;
    int sAl = sA;
    _Float16* d0 = dst0;
    float osc = oscale;
    if (modeSel == 3) {
        const int part = blockIdx.y >> 2;               // 0=Q, 1=K, 2=V
        if (part == 1)      { Ab = A2; sAl = 256; d0 = dst1; oloc0 = og0 - 256; osc = 1.0f; }
        else if (part == 2) { Ab = A2; sAl = 256; mode = 1; oloc0 = og0 - 512; osc = 1.0f; }
    } else if (modeSel == 2) {
        mode = 2;
    }

    const int srow = t >> 3, sslot = t & 7;
    const int schunk = sslot ^ (srow & 7);

    f32x4 acc[2][4] = {};
    const int nk = K / 64;
    int buf = 0;

    {
        #pragma unroll
        for (int c = 0; c < 4; ++c)
            gload16(Ab + (size_t)(n0 + c * 32 + srow) * sAl + schunk * 8,
                    As + c * 2048 + t * 8);
        #pragma unroll
        for (int c = 0; c < 2; ++c)
            gload16(W + (size_t)(og0 + c * 32 + srow) * K + schunk * 8,
                    Bs + c * 2048 + t * 8);
        __asm__ volatile("s_waitcnt vmcnt(0)" ::: "memory");
        __syncthreads();
    }

    #pragma unroll 1
    for (int kt = 0; kt < nk; ++kt) {
        if (kt + 1 < nk) {
            const int k0 = (kt + 1) * 64, nb = buf ^ 1;
            #pragma unroll
            for (int c = 0; c < 4; ++c)
                gload16(Ab + (size_t)(n0 + c * 32 + srow) * sAl + k0 + schunk * 8,
                        As + nb * 8192 + c * 2048 + t * 8);
            #pragma unroll
            for (int c = 0; c < 2; ++c)
                gload16(W + (size_t)(og0 + c * 32 + srow) * K + k0 + schunk * 8,
                        Bs + nb * 4096 + c * 2048 + t * 8);
        }
        #pragma unroll
        for (int ks = 0; ks < 2; ++ks) {
            const int csw = ((ks * 4 + quad) ^ (l16 & 7)) * 8;
            half8 af[2], bf[4];
            #pragma unroll
            for (int i = 0; i < 2; ++i)
                af[i] = *(const half8*)&As[buf * 8192 + (w * 32 + i * 16 + l16) * 64 + csw];
            #pragma unroll
            for (int j = 0; j < 4; ++j)
                bf[j] = *(const half8*)&Bs[buf * 4096 + (j * 16 + l16) * 64 + csw];
            #pragma unroll
            for (int i = 0; i < 2; ++i)
                #pragma unroll
                for (int j = 0; j < 4; ++j)
                    acc[i][j] = __builtin_amdgcn_mfma_f32_16x16x32_f16(af[i], bf[j], acc[i][j], 0, 0, 0);
        }
        if (kt + 1 < nk) {
            __asm__ volatile("s_waitcnt vmcnt(0)" ::: "memory");
            __syncthreads();
            buf ^= 1;
        }
    }

    float bcol[4];
    #pragma unroll
    for (int j = 0; j < 4; ++j) bcol[j] = bias[og0 + j * 16 + l16];

    if (mode == 0) {
        _Float16* Escr = As + w * 2048;
        #pragma unroll
        for (int i = 0; i < 2; ++i) {
            #pragma unroll
            for (int j = 0; j < 4; ++j)
                #pragma unroll
                for (int reg = 0; reg < 4; ++reg) {
                    float v = (acc[i][j][reg] + bcol[j]) * osc;
                    if (relu) v = fmaxf(v, 0.f);
                    Escr[(quad * 4 + reg) * 72 + j * 16 + l16] = (_Float16)v;
                }
            __asm__ volatile("s_waitcnt lgkmcnt(0)" ::: "memory");
            const int row = lane & 15, oseg = (lane >> 4) * 16;
            half8 e0 = *(const half8*)&Escr[row * 72 + oseg];
            half8 e1 = *(const half8*)&Escr[row * 72 + oseg + 8];
            _Float16* dp = d0 + (size_t)(n0 + w * 32 + i * 16 + row) * sOut + oloc0 + oseg;
            *(half8*)dp = e0;
            *(half8*)(dp + 8) = e1;
            __asm__ volatile("s_waitcnt lgkmcnt(0)" ::: "memory");
        }
    } else if (mode == 1) {
        #pragma unroll
        for (int i = 0; i < 2; ++i)
            #pragma unroll
            for (int j = 0; j < 4; ++j) {
                const int c = j * 16 + l16;
                const int mloc = w * 32 + i * 16 + quad * 4;
                const int sw = l16 * 8;
                half4v pv;
                #pragma unroll
                for (int reg = 0; reg < 4; ++reg)
                    pv[reg] = (_Float16)(acc[i][j][reg] + bcol[j]);
                *(half4v*)&As[c * 128 + (mloc ^ sw)] = pv;
            }
        __syncthreads();
        const int n0m = n0 & 2047, bidx = n0 >> 11;
        #pragma unroll
        for (int r = 0; r < 2; ++r) {
            const int c = (t >> 3) + r * 32;
            const int mch = (t & 7) * 16;
            const int sw = (c & 15) * 8;
            half8 v0 = *(const half8*)&As[c * 128 + (mch ^ sw)];
            half8 v1 = *(const half8*)&As[c * 128 + ((mch + 8) ^ sw)];
            _Float16* dp = dst2 + ((size_t)bidx * 256 + oloc0 + c) * (size_t)Mm + n0m + mch;
            *(half8*)dp = v0;
            *(half8*)(dp + 8) = v1;
        }
    } else {
        __syncthreads();
        float* scr = (float*)As;
        #pragma unroll
        for (int i = 0; i < 2; ++i)
            #pragma unroll
            for (int j = 0; j < 4; ++j) {
                const int c = j * 16 + l16;
                const int mloc = w * 32 + i * 16 + quad * 4;
                const int sw = (c & 7) * 4;
                f32x4 v;
                #pragma unroll
                for (int reg = 0; reg < 4; ++reg) v[reg] = acc[i][j][reg] + bcol[j];
                *(f32x4*)&scr[c * 128 + (mloc ^ sw)] = v;
            }
        __syncthreads();
        const int n0m = n0 & 2047, bidx = n0 >> 11;
        #pragma unroll
        for (int r = 0; r < 2; ++r) {
            const int c = (t >> 3) + r * 32;
            const int mch = (t & 7) * 16;
            const int sw = (c & 7) * 4;
            float* dp = dstF + ((size_t)bidx * 256 + og0 + c) * (size_t)Nn + n0m + mch;
            #pragma unroll
            for (int k = 0; k < 4; ++k)
                *(f32x4*)(dp + k * 4) = *(const f32x4*)&scr[c * 128 + ((mch + k * 4) ^ sw)];
        }
    }
}

// ---------------------------------------------------------------------------
// MFMA attention R13: double-buffered LDS via global_load_lds + 1 barrier/iter.
// R7-R12 evidence: attn pinned at 42-45us through conflict/VALU/TLP fixes ->
// the surviving structural term is the 2-barrier single-buffer loop + reg
// round-trip staging (LDS pipe ~22 ds-ops/wave/iter = largest throughput
// term; 16 full-block barriers). Fix (guide T3-lite, m97/m173): gload_lds
// direct-to-LDS with PRE-SWIZZLED global source (linear LDS dest, read-side
// XOR unchanged — both-sides rule), double-buffered K/V, issue next tile at
// iter top, single vmcnt(0)+barrier per iter. Removes 8/16 barriers, the
// whole ds_write phase, and ~8 VGPR. T5 setprio(1) around MFMA clusters
// (m191: +4-7% multi-wave attn).
// Grid 1024 (XCD-aware), 512 thr, LDS 50.4 KB -> 3 blocks/CU.
// ---------------------------------------------------------------------------
__global__ __launch_bounds__(512)
void attn_mfma_kernel(const _Float16* __restrict__ Qp, const _Float16* __restrict__ Kp,
                      const _Float16* __restrict__ Vt,
                      const unsigned int* __restrict__ bmask,
                      _Float16* __restrict__ Oa, _Float16* __restrict__ Ob,
                      _Float16* __restrict__ Oc, _Float16* __restrict__ Od,
                      float* __restrict__ La, float* __restrict__ Lb,
                      float* __restrict__ Lc, float* __restrict__ Ld) {
    __shared__ __align__(16) _Float16 Ks[2][64][64];   // 16384 B, swizzled
    __shared__ __align__(16) _Float16 Vs[2][64][64];   // 16384 B, swizzled
    __shared__ __align__(16) _Float16 Ps[8][16][72];   // 18432 B

    // XCD-aware decomposition: id%8 = XCD slot -> bh pair
    const int id = blockIdx.x;
    const int xcd = id & 7, loc = id >> 3;             // loc 0..127
    const int bh = xcd * 2 + (loc >> 6);               // 0..15
    const int sub = loc & 63;
    const int mquart = sub & 3;
    const int n0 = (sub >> 2) * 128;                   // 16 tiles of 128 rows
    const int b = bh >> 2, h = bh & 3;

    const int t = threadIdx.x;
    const int w = t >> 6, lane = t & 63, quad = lane >> 4, l16 = lane & 15;

    const _Float16* qp = Qp + ((size_t)b * Nn + n0 + w * 16 + l16) * 256 + h * 64 + quad * 8;
    const half8 qa0 = *(const half8*)(qp);
    const half8 qa1 = *(const half8*)(qp + 32);

    const _Float16* Kstg = Kp + (size_t)b * Nn * 256 + h * 64;
    const _Float16* Vstg = Vt + ((size_t)b * 256 + h * 64) * (size_t)Mm;
    // staging: 512 threads; LDS dest LINEAR (t*16B), source chunk pre-swizzled
    // so LDS[r][c] = global[r][c ^ (r&7)] (involution matches read-side XOR).
    const int sr = t >> 3;                             // row 0..63
    const int schunk = (t & 7) ^ (sr & 7);             // pre-swizzled src chunk

    // per-lane bitmask row: q = n0 + w*16 + l16
    const unsigned int* bmRow = bmask + ((size_t)b * Nn + n0 + w * 16 + l16) * (Mm / 32);

    _Float16* Odst = mquart == 0 ? Oa : mquart == 1 ? Ob : mquart == 2 ? Oc : Od;
    float*    Ldst = mquart == 0 ? La : mquart == 1 ? Lb : mquart == 2 ? Lc : Ld;
    const int mbeg = mquart * (Mm / 4);
    constexpr int NIT = (Mm / 4) / 64;                 // 8

    float psum = 0.f;
    f32x4 O[4] = {};

    auto stage_issue = [&](int m0, int nb) {
        gload16(Kstg + (size_t)(m0 + sr) * 256 + schunk * 8,
                (_Float16*)Ks + nb * 4096 + t * 8);
        gload16(Vstg + (size_t)sr * Mm + m0 + schunk * 8,
                (_Float16*)Vs + nb * 4096 + t * 8);
    };

    stage_issue(mbeg, 0);
    __asm__ volatile("s_waitcnt vmcnt(0)" ::: "memory");
    __syncthreads();

    int buf = 0;
    #pragma unroll 1
    for (int it = 0; it < NIT; ++it) {
        const int m0 = mbeg + it * 64;
        if (it + 1 < NIT) stage_issue(m0 + 64, buf ^ 1);   // in flight under compute

        const uint2 bmv = *(const uint2*)(bmRow + (m0 >> 5));

        f32x4 S[4];
        __builtin_amdgcn_s_setprio(1);
        #pragma unroll
        for (int mt = 0; mt < 4; ++mt) {
            const int r = mt * 16 + l16, rs = r & 7;
            half8 k0 = *(const half8*)&Ks[buf][r][(quad ^ rs) * 8];
            half8 k1 = *(const half8*)&Ks[buf][r][((quad + 4) ^ rs) * 8];
            f32x4 z = {0.f, 0.f, 0.f, 0.f};
            z = __builtin_amdgcn_mfma_f32_16x16x32_f16(k0, qa0, z, 0, 0, 0);   // swapped
            z = __builtin_amdgcn_mfma_f32_16x16x32_f16(k1, qa1, z, 0, 0, 0);
            S[mt] = z;
        }
        __builtin_amdgcn_s_setprio(0);

        // p = bit ? exp2(S) : 0 ; pack pairs and write Ps[q=l16][m] (b64s)
        const unsigned losh = bmv.x >> (quad * 4);
        const unsigned hish = bmv.y >> (quad * 4);
        #pragma unroll
        for (int mt = 0; mt < 4; ++mt) {
            const unsigned wb = (mt < 2) ? losh : hish;
            const int sh = (mt & 1) * 16;
            const float p0 = ((wb >> (sh + 0)) & 1u) ? __builtin_exp2f(S[mt][0]) : 0.f;
            const float p1 = ((wb >> (sh + 1)) & 1u) ? __builtin_exp2f(S[mt][1]) : 0.f;
            const float p2 = ((wb >> (sh + 2)) & 1u) ? __builtin_exp2f(S[mt][2]) : 0.f;
            const float p3 = ((wb >> (sh + 3)) & 1u) ? __builtin_exp2f(S[mt][3]) : 0.f;
            psum += (p0 + p1) + (p2 + p3);
            const half2v lo2 = __builtin_bit_cast(half2v, __builtin_amdgcn_cvt_pkrtz(p0, p1));
            const half2v hi2 = __builtin_bit_cast(half2v, __builtin_amdgcn_cvt_pkrtz(p2, p3));
            half4v pv;
            pv[0] = lo2[0]; pv[1] = lo2[1]; pv[2] = hi2[0]; pv[3] = hi2[1];
            *(half4v*)&Ps[w][l16][mt * 16 + quad * 4] = pv;
        }
        __asm__ volatile("s_waitcnt lgkmcnt(0)" ::: "memory");
        half8 pa0 = *(const half8*)&Ps[w][l16][quad * 8];
        half8 pa1 = *(const half8*)&Ps[w][l16][32 + quad * 8];

        __builtin_amdgcn_s_setprio(1);
        #pragma unroll
        for (int dt = 0; dt < 4; ++dt) {
            const int r = dt * 16 + l16, rs = r & 7;
            half8 v0 = *(const half8*)&Vs[buf][r][(quad ^ rs) * 8];
            half8 v1 = *(const half8*)&Vs[buf][r][((quad + 4) ^ rs) * 8];
            O[dt] = __builtin_amdgcn_mfma_f32_16x16x32_f16(pa0, v0, O[dt], 0, 0, 0);
            O[dt] = __builtin_amdgcn_mfma_f32_16x16x32_f16(pa1, v1, O[dt], 0, 0, 0);
        }
        __builtin_amdgcn_s_setprio(0);

        if (it + 1 < NIT) {
            __asm__ volatile("s_waitcnt vmcnt(0)" ::: "memory");
            __syncthreads();
            buf ^= 1;
        }
    }

    // L[q]: sum across the 4 quads holding q=l16's m-chunks
    psum += __shfl_xor(psum, 16);
    psum += __shfl_xor(psum, 32);

    // dense O-store: stage O in this wave's Ps slice (free after last PV),
    // then 16B/lane coalesced stores — full 128B per row, no 32B sectors.
    #pragma unroll
    for (int dt = 0; dt < 4; ++dt)
        #pragma unroll
        for (int reg = 0; reg < 4; ++reg)
            Ps[w][quad * 4 + reg][dt * 16 + l16] = (_Float16)(O[dt][reg] * 0.0625f);
    __asm__ volatile("s_waitcnt lgkmcnt(0)" ::: "memory");
    #pragma unroll
    for (int u2 = 0; u2 < 2; ++u2) {
        const int u = lane * 2 + u2;               // 0..127
        const int r = u >> 3, c = u & 7;           // row 0..15, 16B chunk 0..7
        half8 v = *(const half8*)&Ps[w][r][c * 8];
        *(half8*)(Odst + ((size_t)b * Nn + n0 + w * 16 + r) * 256 + h * 64 + c * 8) = v;
    }
    if (lane < 16)
        Ldst[((size_t)b * Nn + n0 + w * 16 + l16) * 4 + h] = psum * 0.0625f;
}

// ---------------------------------------------------------------------------
// msg-projection with 4-way combine fused into A-staging (reg-staged,
// issue-early/write-late). K=256, out -> Yp cols 256..511. Grid (64, 4).
// ---------------------------------------------------------------------------
__global__ __launch_bounds__(256)
void gemm_msg_kernel(const _Float16* __restrict__ Oa, const _Float16* __restrict__ Ob,
                     const _Float16* __restrict__ Oc, const _Float16* __restrict__ Od,
                     const float* __restrict__ La, const float* __restrict__ Lb,
                     const float* __restrict__ Lc, const float* __restrict__ Ld,
                     const _Float16* __restrict__ W, const float* __restrict__ bias,
                     _Float16* __restrict__ dst) {
    __shared__ __align__(16) _Float16 As[2 * 128 * 64];   // 32 KB
    __shared__ __align__(16) _Float16 Bs[2 * 64 * 64];    // 16 KB

    const int t = threadIdx.x;
    const int w = t >> 6, lane = t & 63, quad = lane >> 4, l16 = lane & 15;
    const int n0 = blockIdx.x * 128;
    const int og0 = blockIdx.y * 64;
    const int srow = t >> 3, sslot = t & 7;
    const int schunk = sslot ^ (srow & 7);
    constexpr int K = 256;

    f32x4 acc[2][4] = {};

    half8 oa[4], ob[4], oc[4], od[4];
    float inv[4];

    auto loadA = [&](int k0) {
        const int h = k0 >> 6;
        #pragma unroll
        for (int c = 0; c < 4; ++c) {
            const size_t row = (size_t)(n0 + c * 32 + srow);
            const size_t off = row * 256 + k0 + schunk * 8;
            oa[c] = *(const half8*)(Oa + off);
            ob[c] = *(const half8*)(Ob + off);
            oc[c] = *(const half8*)(Oc + off);
            od[c] = *(const half8*)(Od + off);
            inv[c] = 1.0f / (La[row * 4 + h] + Lb[row * 4 + h]
                           + Lc[row * 4 + h] + Ld[row * 4 + h]);
        }
    };
    auto writeA = [&](int nb) {
        #pragma unroll
        for (int c = 0; c < 4; ++c) {
            half8 m;
            #pragma unroll
            for (int k = 0; k < 8; ++k)
                m[k] = (_Float16)((((float)oa[c][k] + (float)ob[c][k])
                                 + ((float)oc[c][k] + (float)od[c][k])) * inv[c]);
            *(half8*)&As[nb * 8192 + c * 2048 + t * 8] = m;
        }
    };
    auto loadB = [&](int k0, int nb) {
        #pragma unroll
        for (int c = 0; c < 2; ++c)
            gload16(W + (size_t)(og0 + c * 32 + srow) * K + k0 + schunk * 8,
                    Bs + nb * 4096 + c * 2048 + t * 8);
    };

    loadA(0);
    loadB(0, 0);
    writeA(0);
    __asm__ volatile("s_waitcnt vmcnt(0)" ::: "memory");
    __syncthreads();

    int buf = 0;
    #pragma unroll 1
    for (int kt = 0; kt < 4; ++kt) {
        if (kt < 3) {
            loadA((kt + 1) * 64);
            loadB((kt + 1) * 64, buf ^ 1);
        }
        #pragma unroll
        for (int ks = 0; ks < 2; ++ks) {
            const int csw = ((ks * 4 + quad) ^ (l16 & 7)) * 8;
            half8 af[2], bf[4];
            #pragma unroll
            for (int i = 0; i < 2; ++i)
                af[i] = *(const half8*)&As[buf * 8192 + (w * 32 + i * 16 + l16) * 64 + csw];
            #pragma unroll
            for (int j = 0; j < 4; ++j)
                bf[j] = *(const half8*)&Bs[buf * 4096 + (j * 16 + l16) * 64 + csw];
            #pragma unroll
            for (int i = 0; i < 2; ++i)
                #pragma unroll
                for (int j = 0; j < 4; ++j)
                    acc[i][j] = __builtin_amdgcn_mfma_f32_16x16x32_f16(af[i], bf[j], acc[i][j], 0, 0, 0);
        }
        if (kt < 3) {
            writeA(buf ^ 1);
            __asm__ volatile("s_waitcnt vmcnt(0)" ::: "memory");
            __syncthreads();
            buf ^= 1;
        }
    }

    float bcol[4];
    #pragma unroll
    for (int j = 0; j < 4; ++j) bcol[j] = bias[og0 + j * 16 + l16];

    _Float16* Escr = As + w * 2048;
    #pragma unroll
    for (int i = 0; i < 2; ++i) {
        #pragma unroll
        for (int j = 0; j < 4; ++j)
            #pragma unroll
            for (int reg = 0; reg < 4; ++reg)
                Escr[(quad * 4 + reg) * 72 + j * 16 + l16] =
                    (_Float16)(acc[i][j][reg] + bcol[j]);
        __asm__ volatile("s_waitcnt lgkmcnt(0)" ::: "memory");
        const int row = lane & 15, oseg = (lane >> 4) * 16;
        half8 e0 = *(const half8*)&Escr[row * 72 + oseg];
        half8 e1 = *(const half8*)&Escr[row * 72 + oseg + 8];
        _Float16* dp = dst + (size_t)(n0 + w * 32 + i * 16 + row) * 512 + og0 + oseg;
        *(half8*)dp = e0;
        *(half8*)(dp + 8) = e1;
        __asm__ volatile("s_waitcnt lgkmcnt(0)" ::: "memory");
    }
}

// ---------------------------------------------------------------------------
extern "C" void kernel_launch(void* const* d_in, const int* in_sizes, int n_in,
                              void* d_out, int out_size, void* d_ws, size_t ws_size,
                              hipStream_t stream) {
    const float* x      = (const float*)d_in[0];
    const float* source = (const float*)d_in[1];
    const float* mask   = (const float*)d_in[2];
    const float* Wq = (const float*)d_in[3];
    const float* bq = (const float*)d_in[4];
    const float* Wk = (const float*)d_in[5];
    const float* bk = (const float*)d_in[6];
    const float* Wv = (const float*)d_in[7];
    const float* bv = (const float*)d_in[8];
    const float* Wm = (const float*)d_in[9];
    const float* bm = (const float*)d_in[10];
    const float* W1 = (const float*)d_in[11];
    const float* b1 = (const float*)d_in[12];
    const float* gamma = (const float*)d_in[13];
    const float* beta  = (const float*)d_in[14];
    const float* rmean = (const float*)d_in[15];
    const float* rvar  = (const float*)d_in[16];
    const float* W2 = (const float*)d_in[17];
    const float* b2 = (const float*)d_in[18];
    float* outp = (float*)d_out;

    // workspace layout (bytes)
    char* wsb = (char*)d_ws;
    _Float16* Yp   = (_Float16*)wsb;                       // [8192][512]  8 MB
    _Float16* Sp   = (_Float16*)(wsb + (8u << 20));        // [8192][256]  4 MB (-> O_C after qkv)
    _Float16* Qp   = (_Float16*)(wsb + (12u << 20));       // [8192][256]  4 MB
    _Float16* Kp   = (_Float16*)(wsb + (16u << 20));       // [8192][256]  4 MB
    _Float16* Vt   = (_Float16*)(wsb + (20u << 20));       // [1024][2048] 4 MB
    _Float16* Oa   = (_Float16*)(wsb + (24u << 20));       // [8192][256]  4 MB (O_A)
    _Float16* Hp   = (_Float16*)(wsb + (28u << 20));       // [8192][512]  8 MB (mlp1 out)
    // transients (dead before mlp1 writes Hp):
    unsigned long long* bmask = (unsigned long long*)(wsb + (28u << 20));  // 2 MB
    _Float16* Ob = (_Float16*)(wsb + (30u << 20));                          // 4 MB (O_B)
    float* La = (float*)(wsb + (34u << 20));                                // 128 KB
    float* Lb = (float*)(wsb + (34u << 20) + (128u << 10));                 // 128 KB
    float* Lc = (float*)(wsb + (34u << 20) + (256u << 10));                 // 128 KB
    float* Ld = (float*)(wsb + (34u << 20) + (384u << 10));                 // 128 KB
    _Float16* Oc = Sp;                       // Sp dead after qkv
    _Float16* Od = (_Float16*)outp;          // d_out dead until mlp2 writes it
    char* wp = wsb + (36u << 20);
    _Float16* Wqp  = (_Float16*)wp;            wp += 256 * 256 * 2;
    _Float16* Wkvp = (_Float16*)wp;            wp += 512 * 256 * 2;
    _Float16* Wmp  = (_Float16*)wp;            wp += 256 * 256 * 2;
    _Float16* W1p  = (_Float16*)wp;            wp += 512 * 512 * 2;
    _Float16* W2p  = (_Float16*)wp;            wp += 256 * 512 * 2;
    float* bqp  = (float*)wp;                  wp += 256 * 4;
    float* bkvp = (float*)wp;                  wp += 512 * 4;
    float* b1f  = (float*)wp;                  wp += 512 * 4;

    prep_all_kernel<<<4864, 256, 0, stream>>>(
        Wq, bq, Wk, bk, Wv, bv, Wm, W1, b1, gamma, beta, rmean, rvar, W2, mask,
        x, source, Wqp, bqp, Wkvp, bkvp, Wmp, W1p, b1f, W2p, bmask, Yp, Sp);

    // fused Q/K/V projection: (64, 12) blocks of 128x64.
    // Q pre-scaled by 0.125*log2(e) so attn softmax is a bare v_exp_f32.
    gemm4w_kernel<<<dim3(NT / 128, 12), 256, 0, stream>>>(
        Yp, Sp, Wqp, bqp, Qp, Kp, Vt, nullptr, 256, 512, 256, 3, 0, 0.18033688011f);

    attn_mfma_kernel<<<1024, 512, 0, stream>>>(Qp, Kp, Vt,
                                               (const unsigned int*)bmask,
                                               Oa, Ob, Oc, Od, La, Lb, Lc, Ld);

    // combine + msg projection fused: out -> Yp cols 256..511
    gemm_msg_kernel<<<dim3(NT / 128, 4), 256, 0, stream>>>(
        Oa, Ob, Oc, Od, La, Lb, Lc, Ld, Wmp, bm, Yp + 256);

    // MLP layer 1 (BN-folded, relu): A=Yp [n][512], out Hp [n][512]
    gemm4w_kernel<<<dim3(NT / 128, 8), 256, 0, stream>>>(
        Yp, nullptr, W1p, b1f, Hp, nullptr, nullptr, nullptr, 512, 512, 512, 0, 1, 1.0f);
    // MLP layer 2: A=Hp, fp32 out [b][256][n]
    gemm4w_kernel<<<dim3(NT / 128, 4), 256, 0, stream>>>(
        Hp, nullptr, W2p, b2, nullptr, nullptr, nullptr, outp, 512, 512, 0, 2, 0, 1.0f);
}